// Round 1
// 387.327 us; speedup vs baseline: 1.1991x; 1.1991x over previous
//
#include <hip/hip_runtime.h>

#define N_NODES 8192
#define E_EDGES 524288
#define D_DIM   256
#define NEG_FILL -1e9f

#define PROJ_BLOCKS 256
#define ROWS_PER_BLOCK 32
#define FILL_BLOCKS 1792            // 256 + 1792 = 2048 blocks, one co-resident pass

#define EDGE_BLOCKS 2048
#define EDGES_PER_WAVE 64           // E / (EDGE_BLOCKS * 4 waves)

typedef float vfloat4 __attribute__((ext_vector_type(4)));
typedef float vfloat2 __attribute__((ext_vector_type(2)));

// K1: blocks [0,256) compute A = h@W1[0:256], B = h@W1[256:512] -> fp8 e4m3 ws
// (4 MiB total, L2-resident for K2's gathers); blocks [256,2048) fill ALL of
// out with -1e9 via NT stores. Proj is VALU-bound and hides under the fill.
__global__ __launch_bounds__(256) void fill_proj_kernel(
    const float* __restrict__ h,
    const float* __restrict__ W1,
    float* __restrict__ out,
    unsigned char* __restrict__ AB)
{
    if (blockIdx.x < PROJ_BLOCKS) {
        __shared__ float hs[ROWS_PER_BLOCK * D_DIM];   // 32 KB
        const int t  = threadIdx.x;
        const int r0 = blockIdx.x * ROWS_PER_BLOCK;
        const float* hp = h + (long long)r0 * D_DIM;
        for (int i = t; i < ROWS_PER_BLOCK * D_DIM; i += 256) hs[i] = hp[i];
        __syncthreads();

        float accA[ROWS_PER_BLOCK];
        float accB[ROWS_PER_BLOCK];
        #pragma unroll
        for (int r = 0; r < ROWS_PER_BLOCK; ++r) { accA[r] = 0.f; accB[r] = 0.f; }

        for (int k = 0; k < D_DIM; k += 4) {
            float wa0 = W1[(k + 0) * D_DIM + t];
            float wa1 = W1[(k + 1) * D_DIM + t];
            float wa2 = W1[(k + 2) * D_DIM + t];
            float wa3 = W1[(k + 3) * D_DIM + t];
            float wb0 = W1[(256 + k + 0) * D_DIM + t];
            float wb1 = W1[(256 + k + 1) * D_DIM + t];
            float wb2 = W1[(256 + k + 2) * D_DIM + t];
            float wb3 = W1[(256 + k + 3) * D_DIM + t];
            #pragma unroll
            for (int r = 0; r < ROWS_PER_BLOCK; ++r) {
                const float4 hv = *(const float4*)&hs[r * D_DIM + k];
                accA[r] = fmaf(hv.x, wa0, accA[r]);
                accA[r] = fmaf(hv.y, wa1, accA[r]);
                accA[r] = fmaf(hv.z, wa2, accA[r]);
                accA[r] = fmaf(hv.w, wa3, accA[r]);
                accB[r] = fmaf(hv.x, wb0, accB[r]);
                accB[r] = fmaf(hv.y, wb1, accB[r]);
                accB[r] = fmaf(hv.z, wb2, accB[r]);
                accB[r] = fmaf(hv.w, wb3, accB[r]);
            }
        }

        unsigned char* A = AB;
        unsigned char* B = AB + (long long)N_NODES * D_DIM;
        #pragma unroll
        for (int r = 0; r < ROWS_PER_BLOCK; ++r) {
            int pa = __builtin_amdgcn_cvt_pk_fp8_f32(accA[r], accA[r], 0, false);
            int pb = __builtin_amdgcn_cvt_pk_fp8_f32(accB[r], accB[r], 0, false);
            A[(long long)(r0 + r) * D_DIM + t] = (unsigned char)(pa & 0xFF);
            B[(long long)(r0 + r) * D_DIM + t] = (unsigned char)(pb & 0xFF);
        }
    } else {
        const int b = blockIdx.x - PROJ_BLOCKS;
        const int nvec = (N_NODES / 4) * N_NODES;   // 16777216
        vfloat4 fv = { NEG_FILL, NEG_FILL, NEG_FILL, NEG_FILL };
        vfloat4* o4 = (vfloat4*)out;
        for (int i = b * 256 + threadIdx.x; i < nvec; i += FILL_BLOCKS * 256)
            __builtin_nontemporal_store(fv, &o4[i]);
    }
}

// K2: 2048 blocks x 4 waves; each wave owns 64 consecutive edges.
// NEW STRUCTURE: 16 lanes per edge -> 4 edges processed per wave-iteration
// (16 iterations instead of 64). Each lane covers 16 of the 256 hidden dims:
//  - gathers are dwordx4 (one 16B load per lane per row; 2 wave-loads / 4 edges)
//  - W1-attr-row and W2 slices (16 floats each) hoisted to registers (t-dependent)
//  - reduction is 4 shfl_xor steps per 4 edges (1 crossbar op per edge vs 6)
//  - score stores are NONTEMPORAL so scattered out-lines don't evict the
//    4 MiB AB table from per-XCD L2 (gathers stay L2-resident)
__global__ __launch_bounds__(256) void edge_kernel(
    const int* __restrict__ eidx,
    const float* __restrict__ eattr,
    const float* __restrict__ W1,
    const float* __restrict__ W2,
    const unsigned char* __restrict__ AB,
    float* __restrict__ out)
{
    const int wave = blockIdx.x * 4 + (threadIdx.x >> 6);
    const int lane = threadIdx.x & 63;
    const int g    = lane >> 4;          // group 0..3 (one edge each per iter)
    const int t    = lane & 15;          // lane-in-group: dims [t*16, t*16+16)
    const int base = wave * EDGES_PER_WAVE;

    // this wave's 64 edges, one per lane (3 coalesced loads)
    const int   l_all = eidx[base + lane];
    const int   r_all = eidx[E_EDGES + base + lane];
    const float a_all = eattr[base + lane];

    const int j0 = t * 16;
    const float4 wl0 = *(const float4*)&W1[512 * D_DIM + j0 + 0];
    const float4 wl1 = *(const float4*)&W1[512 * D_DIM + j0 + 4];
    const float4 wl2 = *(const float4*)&W1[512 * D_DIM + j0 + 8];
    const float4 wl3 = *(const float4*)&W1[512 * D_DIM + j0 + 12];
    const float4 w20 = *(const float4*)&W2[j0 + 0];
    const float4 w21 = *(const float4*)&W2[j0 + 4];
    const float4 w22 = *(const float4*)&W2[j0 + 8];
    const float4 w23 = *(const float4*)&W2[j0 + 12];
    const unsigned char* Bt = AB + (long long)N_NODES * D_DIM;

    // prime the pipeline with edges 0..3 (one per group)
    int   l_c  = __shfl(l_all, g);
    int   r_c  = __shfl(r_all, g);
    float at_c = __shfl(a_all, g);
    uint4 av_c = *(const uint4*)(AB + (unsigned)l_c * D_DIM + j0);
    uint4 bv_c = *(const uint4*)(Bt + (unsigned)r_c * D_DIM + j0);

    #pragma unroll 4
    for (int i = 0; i < EDGES_PER_WAVE / 4; ++i) {
        const int   l_cur = l_c;
        const int   r_cur = r_c;
        const float attr  = at_c;
        const uint4 av    = av_c;
        const uint4 bv    = bv_c;
        if (i + 1 < EDGES_PER_WAVE / 4) {    // issue next gathers before compute
            l_c  = __shfl(l_all, 4 * (i + 1) + g);
            r_c  = __shfl(r_all, 4 * (i + 1) + g);
            at_c = __shfl(a_all, 4 * (i + 1) + g);
            av_c = *(const uint4*)(AB + (unsigned)l_c * D_DIM + j0);
            bv_c = *(const uint4*)(Bt + (unsigned)r_c * D_DIM + j0);
        }

        float s = 0.f;
        #define MLP_STEP(AV, BV, WL, W2V) {                                        \
            vfloat2 alo = __builtin_amdgcn_cvt_pk_f32_fp8((int)(AV), false);       \
            vfloat2 ahi = __builtin_amdgcn_cvt_pk_f32_fp8((int)(AV), true);        \
            vfloat2 blo = __builtin_amdgcn_cvt_pk_f32_fp8((int)(BV), false);       \
            vfloat2 bhi = __builtin_amdgcn_cvt_pk_f32_fp8((int)(BV), true);        \
            float hv;                                                              \
            hv = fmaf(attr, WL.x, alo.x + blo.x); hv = fmaxf(hv, 0.f); s = fmaf(hv, W2V.x, s); \
            hv = fmaf(attr, WL.y, alo.y + blo.y); hv = fmaxf(hv, 0.f); s = fmaf(hv, W2V.y, s); \
            hv = fmaf(attr, WL.z, ahi.x + bhi.x); hv = fmaxf(hv, 0.f); s = fmaf(hv, W2V.z, s); \
            hv = fmaf(attr, WL.w, ahi.y + bhi.y); hv = fmaxf(hv, 0.f); s = fmaf(hv, W2V.w, s); \
        }
        MLP_STEP(av.x, bv.x, wl0, w20);
        MLP_STEP(av.y, bv.y, wl1, w21);
        MLP_STEP(av.z, bv.z, wl2, w22);
        MLP_STEP(av.w, bv.w, wl3, w23);
        #undef MLP_STEP

        // reduce the 16-lane partial sums within each group
        s += __shfl_xor(s, 8);
        s += __shfl_xor(s, 4);
        s += __shfl_xor(s, 2);
        s += __shfl_xor(s, 1);

        if (t == 0)
            __builtin_nontemporal_store(
                s, &out[(long long)l_cur * N_NODES + r_cur]);
    }
}

extern "C" void kernel_launch(void* const* d_in, const int* in_sizes, int n_in,
                              void* d_out, int out_size, void* d_ws, size_t ws_size,
                              hipStream_t stream) {
    // inputs: 0=encoded (unused), 1=h, 2=edge_index, 3=edge_attr, 4=W1, 5=W2
    const float* h     = (const float*)d_in[1];
    const int*   eidx  = (const int*)d_in[2];
    const float* eattr = (const float*)d_in[3];
    const float* W1    = (const float*)d_in[4];
    const float* W2    = (const float*)d_in[5];
    float* out = (float*)d_out;
    unsigned char* AB = (unsigned char*)d_ws;   // 4 MiB (2 * N * D fp8)

    fill_proj_kernel<<<PROJ_BLOCKS + FILL_BLOCKS, 256, 0, stream>>>(h, W1, out, AB);
    edge_kernel<<<EDGE_BLOCKS, 256, 0, stream>>>(eidx, eattr, W1, W2, AB, out);
}